// Round 7
// baseline (102.210 us; speedup 1.0000x reference)
//
#include <hip/hip_runtime.h>
#include <math.h>

// Problem constants
#define M_TOKENS 16384               // B*S = 4*4096
#define E_EXPERTS 64
#define K_DIM 2048
#define KSPLIT 4
#define KCHUNK (K_DIM / KSPLIT)      // 512
#define ESPLIT 2
#define EPW (E_EXPERTS / ESPLIT)     // 32 experts per wave
#define PSTRIDE (KSPLIT * E_EXPERTS) // 256 floats per token in partials
#define TPBLK 256                    // tokens per block (4 subgroups x 64)

// ---------------------------------------------------------------------------
// Gates kernel — round-3 dataflow (lane=token, W wave-uniform scalar s_load,
// x per-lane VMEM, zero LDS), product KSPLIT*ESPLIT = 8 (TA-line floor
// ~45 us), with the latency fix round 6 failed to get:
//  - __launch_bounds__(512, 2): allow ~256 VGPR -> compiler keeps the deep
//    prefetch (round 6's VGPR=40 showed it was dropped under default bounds).
//  - 8-deep float4 rotation (8 named buffers): load-to-use distance
//    = 7 groups x 256 FMA-cyc = 1792 cyc >> 900-cyc HBM latency.
//  - block = 512 thr = 8 waves = 4 token-subgroups x 2 expert-halves;
//    grid = 256 blocks = 1 block/CU -> 8 waves/CU (2/SIMD).
//  - FMA chain per (token, expert, kc): k-ascending, KSPLIT=4, reduce order
//    unchanged -> summation bit-identical to rounds 1/3/6 (absmax 0).
// ---------------------------------------------------------------------------
__global__ __launch_bounds__(512, 2) void gates_kernel(
    const float* __restrict__ x, const float* __restrict__ W,
    float* __restrict__ part) {
  const int tid = threadIdx.x;
  const int lane = tid & 63;
  const int w = __builtin_amdgcn_readfirstlane(tid >> 6);
  const int eh = w & 1;              // expert half
  const int tsub = w >> 1;           // token subgroup (0..3)
  const int tg = blockIdx.x >> 2;
  const int kc = blockIdx.x & 3;
  const int t = tg * TPBLK + tsub * 64 + lane;
  const int kbase = kc * KCHUNK;

  const float* xp = x + (size_t)t * K_DIM + kbase;
  const float* wp = W + (size_t)kbase * E_EXPERTS + eh * EPW;

  float acc[EPW];
#pragma unroll
  for (int e = 0; e < EPW; ++e) acc[e] = 0.0f;

  // 8-deep prefetch rotation
  float4 b0 = *reinterpret_cast<const float4*>(xp + 0);
  float4 b1 = *reinterpret_cast<const float4*>(xp + 4);
  float4 b2 = *reinterpret_cast<const float4*>(xp + 8);
  float4 b3 = *reinterpret_cast<const float4*>(xp + 12);
  float4 b4 = *reinterpret_cast<const float4*>(xp + 16);
  float4 b5 = *reinterpret_cast<const float4*>(xp + 20);
  float4 b6 = *reinterpret_cast<const float4*>(xp + 24);
  float4 b7 = *reinterpret_cast<const float4*>(xp + 28);

#define FMA4(bv, kofs)                                                        \
  do {                                                                        \
    const float* wr0 = wp + (size_t)(kofs)*E_EXPERTS;                         \
    float xs[4] = {bv.x, bv.y, bv.z, bv.w};                                   \
    _Pragma("unroll") for (int kk = 0; kk < 4; ++kk) {                        \
      const float* wr = wr0 + kk * E_EXPERTS;                                 \
      _Pragma("unroll") for (int e = 0; e < EPW; ++e)                         \
        acc[e] = fmaf(xs[kk], wr[e], acc[e]);                                 \
    }                                                                         \
  } while (0)

  // 512 k = 16 groups of 32; last group peeled (no prefetch -> no OOB reads)
  for (int g = 0; g < KCHUNK / 32 - 1; ++g) {
    const int k0 = g * 32;
    FMA4(b0, k0 + 0);  b0 = *reinterpret_cast<const float4*>(xp + k0 + 32);
    FMA4(b1, k0 + 4);  b1 = *reinterpret_cast<const float4*>(xp + k0 + 36);
    FMA4(b2, k0 + 8);  b2 = *reinterpret_cast<const float4*>(xp + k0 + 40);
    FMA4(b3, k0 + 12); b3 = *reinterpret_cast<const float4*>(xp + k0 + 44);
    FMA4(b4, k0 + 16); b4 = *reinterpret_cast<const float4*>(xp + k0 + 48);
    FMA4(b5, k0 + 20); b5 = *reinterpret_cast<const float4*>(xp + k0 + 52);
    FMA4(b6, k0 + 24); b6 = *reinterpret_cast<const float4*>(xp + k0 + 56);
    FMA4(b7, k0 + 28); b7 = *reinterpret_cast<const float4*>(xp + k0 + 60);
  }
  {
    const int k0 = KCHUNK - 32;
    FMA4(b0, k0 + 0);
    FMA4(b1, k0 + 4);
    FMA4(b2, k0 + 8);
    FMA4(b3, k0 + 12);
    FMA4(b4, k0 + 16);
    FMA4(b5, k0 + 20);
    FMA4(b6, k0 + 24);
    FMA4(b7, k0 + 28);
  }
#undef FMA4

  // epilogue: 8 float4 stores, contiguous 32 floats per lane
  float* p = part + (size_t)t * PSTRIDE + kc * E_EXPERTS + eh * EPW;
#pragma unroll
  for (int v = 0; v < EPW / 4; ++v) {
    *reinterpret_cast<float4*>(p + v * 4) =
        make_float4(acc[4 * v + 0], acc[4 * v + 1], acc[4 * v + 2],
                    acc[4 * v + 3]);
  }
}

// ---------------------------------------------------------------------------
// Reduce + bias + top-2 + softmax (unchanged from round 3 — passed exact).
// ---------------------------------------------------------------------------
__global__ __launch_bounds__(64) void reduce_topk_kernel(
    const float* __restrict__ part, const float* __restrict__ bias,
    float* __restrict__ out) {
  const int t = blockIdx.x * 64 + threadIdx.x;
  const float4* p = reinterpret_cast<const float4*>(part + (size_t)t * PSTRIDE);
  const float4* b4 = reinterpret_cast<const float4*>(bias);

  float m1 = -INFINITY, m2 = -INFINITY;
  int i1 = 0, i2 = 0;

#pragma unroll 4
  for (int e4 = 0; e4 < 16; ++e4) {
    float4 a = p[e4];        // kc = 0
    float4 b = p[16 + e4];   // kc = 1
    float4 c = p[32 + e4];   // kc = 2
    float4 d = p[48 + e4];   // kc = 3
    float4 bb = b4[e4];
    float g[4];
    g[0] = bb.x + a.x; g[0] += b.x; g[0] += c.x; g[0] += d.x;
    g[1] = bb.y + a.y; g[1] += b.y; g[1] += c.y; g[1] += d.y;
    g[2] = bb.z + a.z; g[2] += b.z; g[2] += c.z; g[2] += d.z;
    g[3] = bb.w + a.w; g[3] += b.w; g[3] += c.w; g[3] += d.w;
#pragma unroll
    for (int j = 0; j < 4; ++j) {
      int e = e4 * 4 + j;
      if (g[j] > m1) {
        m2 = m1; i2 = i1;
        m1 = g[j]; i1 = e;
      } else if (g[j] > m2) {
        m2 = g[j]; i2 = e;
      }
    }
  }

  float w0 = 1.0f / (1.0f + expf(m2 - m1));
  out[2 * t + 0] = w0;
  out[2 * t + 1] = 1.0f - w0;
  float* oidx = out + 2 * (size_t)M_TOKENS;
  oidx[2 * t + 0] = (float)i1;
  oidx[2 * t + 1] = (float)i2;
}

// ---------------------------------------------------------------------------
// Fallback (proven correct in round 1): fully fused, no workspace.
// ---------------------------------------------------------------------------
__global__ __launch_bounds__(64) void router_fused_kernel(
    const float* __restrict__ x, const float* __restrict__ W,
    const float* __restrict__ bias, float* __restrict__ out) {
  const int t = blockIdx.x * 64 + threadIdx.x;
  const float* xrow = x + (size_t)t * K_DIM;

  float acc[E_EXPERTS];
#pragma unroll
  for (int e = 0; e < E_EXPERTS; ++e) acc[e] = 0.0f;

  for (int k4 = 0; k4 < K_DIM; k4 += 4) {
    float4 xv = *reinterpret_cast<const float4*>(xrow + k4);
    float xs[4] = {xv.x, xv.y, xv.z, xv.w};
#pragma unroll
    for (int kk = 0; kk < 4; ++kk) {
      const float* wrow = W + (size_t)(k4 + kk) * E_EXPERTS;
#pragma unroll
      for (int e = 0; e < E_EXPERTS; ++e) acc[e] = fmaf(xs[kk], wrow[e], acc[e]);
    }
  }

  float m1 = -INFINITY, m2 = -INFINITY;
  int i1 = 0, i2 = 0;
#pragma unroll
  for (int e = 0; e < E_EXPERTS; ++e) {
    float g = acc[e] + bias[e];
    if (g > m1) {
      m2 = m1; i2 = i1;
      m1 = g; i1 = e;
    } else if (g > m2) {
      m2 = g; i2 = e;
    }
  }

  float w0 = 1.0f / (1.0f + expf(m2 - m1));
  out[2 * t + 0] = w0;
  out[2 * t + 1] = 1.0f - w0;
  float* oidx = out + 2 * (size_t)M_TOKENS;
  oidx[2 * t + 0] = (float)i1;
  oidx[2 * t + 1] = (float)i2;
}

extern "C" void kernel_launch(void* const* d_in, const int* in_sizes, int n_in,
                              void* d_out, int out_size, void* d_ws, size_t ws_size,
                              hipStream_t stream) {
  const float* x = (const float*)d_in[0];
  const float* W = (const float*)d_in[1];
  const float* b = (const float*)d_in[2];
  float* out = (float*)d_out;

  const size_t need = (size_t)M_TOKENS * PSTRIDE * sizeof(float);
  if (ws_size >= need) {
    float* part = (float*)d_ws;
    gates_kernel<<<(M_TOKENS / TPBLK) * KSPLIT, 512, 0, stream>>>(x, W, part);
    reduce_topk_kernel<<<M_TOKENS / 64, 64, 0, stream>>>(part, b, out);
  } else {
    router_fused_kernel<<<M_TOKENS / 64, 64, 0, stream>>>(x, W, b, out);
  }
}